// Round 16
// baseline (93.184 us; speedup 1.0000x reference)
//
#include <hip/hip_runtime.h>
#include <math.h>

// Problem constants (match reference)
static constexpr int Bn  = 256;   // batch
static constexpr int Dd  = 2048;  // feature dim
static constexpr int ATT = 512;   // attribute dim
static constexpr int Cc  = 1024;  // classes
static constexpr int NG  = 32;    // label groups
static constexpr int CAP = 20;    // LDS-resident P rows per group (fallback: global)
static constexpr int SK1 = 16;    // split-K slices GEMM1 (K=2048, chunk 128)
static constexpr int SK2 = 8;     // split-K slices GEMM2 (K=512,  chunk 64)
static constexpr int BM = 128, BN = 64, BK = 32;
static constexpr int APITCH = 40; // LDS row pitch in halfwords (80B; <=2-way bank alias)
// TEMP=4 -> 1/TEMP=0.25, TEMP^2=16 ; SCALE=20 ; SCALE/TEMP=5

typedef __attribute__((ext_vector_type(8))) short short8v;  // 8 bf16 (MFMA A/B frag)
typedef __attribute__((ext_vector_type(4))) float f32x4;    // MFMA C/D frag

// ---------------- reductions (blockDim.x == 256) ----------------
__device__ __forceinline__ float wave_reduce_sum(float v) {
#pragma unroll
    for (int off = 32; off; off >>= 1) v += __shfl_down(v, off, 64);
    return v;
}
__device__ __forceinline__ float wave_reduce_max(float v) {
#pragma unroll
    for (int off = 32; off; off >>= 1) v = fmaxf(v, __shfl_down(v, off, 64));
    return v;
}
__device__ __forceinline__ float block_reduce_sum(float v) {
    __shared__ float sm_s[4];
    v = wave_reduce_sum(v);
    __syncthreads();                 // protect sm_s reuse across calls
    if ((threadIdx.x & 63) == 0) sm_s[threadIdx.x >> 6] = v;
    __syncthreads();
    return sm_s[0] + sm_s[1] + sm_s[2] + sm_s[3];
}
__device__ __forceinline__ float block_reduce_max(float v) {
    __shared__ float sm_m[4];
    v = wave_reduce_max(v);
    __syncthreads();
    if ((threadIdx.x & 63) == 0) sm_m[threadIdx.x >> 6] = v;
    __syncthreads();
    return fmaxf(fmaxf(sm_m[0], sm_m[1]), fmaxf(sm_m[2], sm_m[3]));
}

// ---------------- f32 -> bf16 hi/lo split (truncation; lo = next 8 bits) ----
__device__ __forceinline__ void splitbf(float v, unsigned short& h, unsigned short& l) {
    const unsigned int b = __float_as_uint(v);
    h = (unsigned short)(b >> 16);
    const float r = v - __uint_as_float(b & 0xFFFF0000u);
    l = (unsigned short)(__float_as_uint(r) >> 16);
}
__device__ __forceinline__ void stage4(const float4 v, unsigned short* hi,
                                       unsigned short* lo, int off) {
    unsigned short h0, h1, h2, h3, l0, l1, l2, l3;
    splitbf(v.x, h0, l0); splitbf(v.y, h1, l1);
    splitbf(v.z, h2, l2); splitbf(v.w, h3, l3);
    *(ushort4*)(hi + off) = make_ushort4(h0, h1, h2, h3);
    *(ushort4*)(lo + off) = make_ushort4(l0, l1, l2, l3);
}

// ------- split-bf16 MFMA tile: 128x64 of C = A[M,K].B[N,K]^T over K-chunk.
// 3 MFMA terms (hi*hi + hi*lo + lo*hi), f32 acc -> ~2^-17 rel error. R12-proven.
__device__ __forceinline__ void gemm_tile_mfma(const float* __restrict__ A,
                                               const float* __restrict__ B,
                                               float* __restrict__ dst, int N, int K,
                                               int row0, int col0, int kbase, int kc,
                                               unsigned short* __restrict__ Ahi,
                                               unsigned short* __restrict__ Alo,
                                               unsigned short* __restrict__ Bhi,
                                               unsigned short* __restrict__ Blo) {
    constexpr int FA = BK / 4;               // 8 float4 per row K-tile
    constexpr int NA = BM * FA / 256;        // 4 per-thread A float4
    constexpr int NB = BN * FA / 256;        // 2 per-thread B float4
    const int tid = threadIdx.x;
    const int lane = tid & 63, wv = tid >> 6;
    const int fr = lane & 15, fg = lane >> 4;

    float4 pa[NA], pb[NB];
#pragma unroll
    for (int u = 0; u < NA; ++u) {
        const int t = tid + u * 256, r = t / FA, c4 = (t % FA) * 4;
        pa[u] = *(const float4*)(A + (size_t)(row0 + r) * K + kbase + c4);
    }
#pragma unroll
    for (int u = 0; u < NB; ++u) {
        const int t = tid + u * 256, r = t / FA, c4 = (t % FA) * 4;
        pb[u] = *(const float4*)(B + (size_t)(col0 + r) * K + kbase + c4);
    }
    f32x4 acc[2][4] = {};
    for (int k0 = kbase; k0 < kbase + kc; k0 += BK) {
        __syncthreads();                     // LDS reuse guard
#pragma unroll
        for (int u = 0; u < NA; ++u) {
            const int t = tid + u * 256, r = t / FA, c4 = (t % FA) * 4;
            stage4(pa[u], Ahi, Alo, r * APITCH + c4);
        }
#pragma unroll
        for (int u = 0; u < NB; ++u) {
            const int t = tid + u * 256, r = t / FA, c4 = (t % FA) * 4;
            stage4(pb[u], Bhi, Blo, r * APITCH + c4);
        }
        __syncthreads();
        if (k0 + BK < kbase + kc) {          // prefetch next K-tile into regs
            const int kn = k0 + BK;
#pragma unroll
            for (int u = 0; u < NA; ++u) {
                const int t = tid + u * 256, r = t / FA, c4 = (t % FA) * 4;
                pa[u] = *(const float4*)(A + (size_t)(row0 + r) * K + kn + c4);
            }
#pragma unroll
            for (int u = 0; u < NB; ++u) {
                const int t = tid + u * 256, r = t / FA, c4 = (t % FA) * 4;
                pb[u] = *(const float4*)(B + (size_t)(col0 + r) * K + kn + c4);
            }
        }
        short8v ah[2], al[2];
#pragma unroll
        for (int im = 0; im < 2; ++im) {
            const int mrow = (wv * 2 + im) * 16 + fr;
            ah[im] = *(short8v*)(Ahi + mrow * APITCH + fg * 8);
            al[im] = *(short8v*)(Alo + mrow * APITCH + fg * 8);
        }
#pragma unroll
        for (int in = 0; in < 4; ++in) {
            const int nrow = in * 16 + fr;
            const short8v bh = *(short8v*)(Bhi + nrow * APITCH + fg * 8);
            const short8v bl = *(short8v*)(Blo + nrow * APITCH + fg * 8);
#pragma unroll
            for (int im = 0; im < 2; ++im) {
                acc[im][in] = __builtin_amdgcn_mfma_f32_16x16x32_bf16(ah[im], bh, acc[im][in], 0, 0, 0);
                acc[im][in] = __builtin_amdgcn_mfma_f32_16x16x32_bf16(ah[im], bl, acc[im][in], 0, 0, 0);
                acc[im][in] = __builtin_amdgcn_mfma_f32_16x16x32_bf16(al[im], bh, acc[im][in], 0, 0, 0);
            }
        }
    }
    // epilogue: D col=lane&15, row=(lane>>4)*4+reg  [m89-verified]
#pragma unroll
    for (int im = 0; im < 2; ++im)
#pragma unroll
        for (int in = 0; in < 4; ++in)
#pragma unroll
            for (int r = 0; r < 4; ++r) {
                const int m = row0 + (wv * 2 + im) * 16 + fg * 4 + r;
                const int c = col0 + in * 16 + fr;
                dst[(size_t)m * N + c] = acc[im][in][r];
            }
}

// ---- K1: bid<256 -> GEMM1 split-K tile (8x2x16); bid>=256 -> sa=l2norm(seen)
__global__ __launch_bounds__(256, 2) void k1_gemm1_sanorm(const float* __restrict__ x,
                                                          const float* __restrict__ W,
                                                          const float* __restrict__ seen,
                                                          float* __restrict__ part,
                                                          float* __restrict__ sa,
                                                          int* __restrict__ doneCnt) {
    __shared__ unsigned short AhiS[BM * APITCH];
    __shared__ unsigned short AloS[BM * APITCH];
    __shared__ unsigned short BhiS[BN * APITCH];
    __shared__ unsigned short BloS[BN * APITCH];
    const int bid = blockIdx.x, tid = threadIdx.x;
    if (bid < 256) {
        const int bx = bid & 7, by = (bid >> 3) & 1, bz = bid >> 4;   // 8 x 2 x 16
        gemm_tile_mfma(x, W, part + (size_t)bz * Bn * ATT, ATT, Dd,
                       by * BM, bx * BN, bz * (Dd / SK1), Dd / SK1,
                       AhiS, AloS, BhiS, BloS);
    } else {
        if (bid == 256 && tid == 0) *doneCnt = 0;   // reset k45 completion counter
#pragma unroll
        for (int u = 0; u < 4; ++u) {
            const int r = (bid - 256) * 4 + u, c = tid * 2;
            const float2 v = *(const float2*)(seen + (size_t)r * ATT + c);
            float ss = block_reduce_sum(fmaf(v.x, v.x, v.y * v.y));
            const float sc = 1.0f / fmaxf(sqrtf(ss), 1e-12f);
            *(float2*)(sa + (size_t)r * ATT + c) = make_float2(v.x * sc, v.y * sc);
        }
    }
}

// ---- K2: ya[m] = l2norm(bias + sum_z part1[z][m][:])  (block per row)
__global__ __launch_bounds__(256) void k2_yanorm(const float* __restrict__ part,
                                                 const float* __restrict__ bias,
                                                 float* __restrict__ ya) {
    const int m = blockIdx.x, c = threadIdx.x * 2;
    float2 s = *(const float2*)(bias + c);
#pragma unroll
    for (int z = 0; z < SK1; ++z) {
        const float2 p = *(const float2*)(part + (size_t)z * Bn * ATT + (size_t)m * ATT + c);
        s.x += p.x; s.y += p.y;
    }
    float ss = block_reduce_sum(fmaf(s.x, s.x, s.y * s.y));
    const float sc = 1.0f / fmaxf(sqrtf(ss), 1e-12f);
    *(float2*)(ya + (size_t)m * ATT + c) = make_float2(s.x * sc, s.y * sc);
}

// ---- K3: GEMM2 split-K (16 x 2 x 8 = 256 blocks, KC=64)
__global__ __launch_bounds__(256, 2) void k3_gemm2(const float* __restrict__ ya,
                                                   const float* __restrict__ sa,
                                                   float* __restrict__ part) {
    __shared__ unsigned short AhiS[BM * APITCH];
    __shared__ unsigned short AloS[BM * APITCH];
    __shared__ unsigned short BhiS[BN * APITCH];
    __shared__ unsigned short BloS[BN * APITCH];
    const int bid = blockIdx.x;
    const int bx = bid & 15, by = (bid >> 4) & 1, bz = bid >> 5;   // 16 x 2 x 8
    gemm_tile_mfma(ya, sa, part + (size_t)bz * Bn * Cc, Cc, ATT,
                   by * BM, bx * BN, bz * (ATT / SK2), ATT / SK2,
                   AhiS, AloS, BhiS, BloS);
}

// ---- K45: one block per label group g. Phase A: softmax for the group's rows
// (reduce part slices -> logits/TEMP softmax -> P in LDS (cap CAP, else global),
// negH in LDS). Phase B: all within-group pairs, per-thread deferred cross-term,
// ONE block reduction. Last-of-32 block finalizes (signal-only counter).
// JS_ij = 0.5*(negH_i + negH_j - sum_c (P_i+P_j)*log((P_i+P_j)/2))
__global__ __launch_bounds__(256) void k45_group_js(const float* __restrict__ part,
                                                    const int* __restrict__ labels,
                                                    float* __restrict__ Pglob,
                                                    float* __restrict__ gSum,
                                                    float* __restrict__ gCnt,
                                                    int* __restrict__ doneCnt,
                                                    float* __restrict__ out) {
    const int g = blockIdx.x, tid = threadIdx.x;
    __shared__ float Psm[CAP][Cc];   // 80 KB
    __shared__ float nh_s[Bn];
    __shared__ int   rows[Bn];
    __shared__ int   lblS[Bn];
    __shared__ int   ng_s;
    __shared__ int   isLast;

    lblS[tid] = labels[tid];
    __syncthreads();
    if (tid == 0) {                  // deterministic serial row-list build
        int n = 0;
        for (int j = 0; j < Bn; ++j)
            if (lblS[j] == g) rows[n++] = j;
        ng_s = n;
    }
    __syncthreads();
    const int ng = ng_s;

    // ---- Phase A: softmax per group row (identical math to old k4)
    const int c = tid * 4;
    for (int idx = 0; idx < ng; ++idx) {
        const int i = rows[idx];
        float4 a = make_float4(0.f, 0.f, 0.f, 0.f);
#pragma unroll
        for (int z = 0; z < SK2; ++z) {
            const float4 p = *(const float4*)(part + (size_t)z * Bn * Cc + (size_t)i * Cc + c);
            a.x += p.x; a.y += p.y; a.z += p.z; a.w += p.w;
        }
        float lv[4] = {a.x * 5.0f, a.y * 5.0f, a.z * 5.0f, a.w * 5.0f};
        float lm = fmaxf(fmaxf(lv[0], lv[1]), fmaxf(lv[2], lv[3]));
        lm = block_reduce_max(lm);
        float se = 0.f;
#pragma unroll
        for (int k = 0; k < 4; ++k) se += __expf(lv[k] - lm);
        se = block_reduce_sum(se);
        const float logZ = __logf(se);
        float nh = 0.f;
        float4 pv;
#pragma unroll
        for (int k = 0; k < 4; ++k) {
            const float lp = lv[k] - lm - logZ;
            const float p = __expf(lp);
            (&pv.x)[k] = p;
            nh = fmaf(p, lp, nh);
        }
        if (idx < CAP) *(float4*)(&Psm[idx][c]) = pv;
        else           *(float4*)(Pglob + (size_t)i * Cc + c) = pv;  // rare fallback
        nh = block_reduce_sum(nh);
        if (tid == 0) nh_s[idx] = nh;
    }
    __syncthreads();                 // P rows + negH visible block-wide

    // ---- Phase B: all pairs within group, deferred accumulation
    float tsum = 0.f;
    float nsum = 0.f, cnt = 0.f;     // tid 0 bookkeeping
    for (int a2 = 0; a2 < ng; ++a2) {
        const float4 pa = (a2 < CAP) ? *(const float4*)(&Psm[a2][c])
                                     : *(const float4*)(Pglob + (size_t)rows[a2] * Cc + c);
        for (int b2 = a2 + 1; b2 < ng; ++b2) {
            const float4 pb = (b2 < CAP) ? *(const float4*)(&Psm[b2][c])
                                         : *(const float4*)(Pglob + (size_t)rows[b2] * Cc + c);
            float t;
            t = pa.x + pb.x; tsum = fmaf(t, __logf(0.5f * t), tsum);
            t = pa.y + pb.y; tsum = fmaf(t, __logf(0.5f * t), tsum);
            t = pa.z + pb.z; tsum = fmaf(t, __logf(0.5f * t), tsum);
            t = pa.w + pb.w; tsum = fmaf(t, __logf(0.5f * t), tsum);
            if (tid == 0) { nsum += nh_s[a2] + nh_s[b2]; cnt += 1.0f; }
        }
    }
    const float s = block_reduce_sum(tsum);       // ONE reduction for the group
    if (tid == 0) {
        gSum[g] = 0.5f * (nsum - s);
        gCnt[g] = cnt;
        __threadfence();                          // publish before signaling
        isLast = (atomicAdd(doneCnt, 1) == NG - 1);
    }
    __syncthreads();
    if (isLast) {
        __threadfence();                          // acquire others' results
        float fs = block_reduce_sum((tid < NG) ? gSum[tid] : 0.0f);
        __syncthreads();
        const float fc = block_reduce_sum((tid < NG) ? gCnt[tid] : 0.0f);
        if (tid == 0) out[0] = (fc == 0.0f) ? 0.0f : (fs / fc) * 16.0f;  // * TEMP^2
    }
}

extern "C" void kernel_launch(void* const* d_in, const int* in_sizes, int n_in,
                              void* d_out, int out_size, void* d_ws, size_t ws_size,
                              hipStream_t stream) {
    const float* x      = (const float*)d_in[0];  // [256, 2048]
    const int*   labels = (const int*)d_in[1];    // [256]
    const float* W      = (const float*)d_in[2];  // [512, 2048]
    const float* bias   = (const float*)d_in[3];  // [512]
    const float* seen   = (const float*)d_in[4];  // [1024, 512]
    float* out = (float*)d_out;

    char* ws = (char*)d_ws;
    // 8 MB split-K partial region: GEMM1 (16x256x512) then GEMM2 (8x256x1024)
    float* part    = (float*)(ws);                              // 8 MB
    float* sa      = (float*)(ws + (8u << 20));                 // 2 MB
    float* ya      = (float*)(ws + (10u << 20));                // 512 KB
    float* Pglob   = (float*)(ws + (10u << 20) + (512u << 10)); // 1 MB (fallback only)
    float* gSum    = (float*)(ws + (11u << 20) + (512u << 10)); // 32 f32
    float* gCnt    = gSum + NG;                                 // 32 f32
    int*   doneCnt = (int*)(gCnt + NG);                         // 1 int

    k1_gemm1_sanorm<<<512, 256, 0, stream>>>(x, W, seen, part, sa, doneCnt);
    k2_yanorm<<<Bn, 256, 0, stream>>>(part, bias, ya);
    k3_gemm2<<<256, 256, 0, stream>>>(ya, sa, part);
    k45_group_js<<<NG, 256, 0, stream>>>(part, labels, Pglob, gSum, gCnt, doneCnt, out);
}

// Round 17
// 51.306 us; speedup vs baseline: 1.8162x; 1.8162x over previous
//
#include <hip/hip_runtime.h>
#include <math.h>

// Problem constants (match reference)
static constexpr int Bn  = 256;   // batch
static constexpr int Dd  = 2048;  // feature dim
static constexpr int ATT = 512;   // attribute dim
static constexpr int Cc  = 1024;  // classes
static constexpr int SK1 = 16;    // split-K slices GEMM1 (K=2048, chunk 128)
static constexpr int SK2 = 8;     // split-K slices GEMM2 (K=512,  chunk 64)
static constexpr int BM = 128, BN = 64, BK = 32;
static constexpr int APITCH = 40; // LDS row pitch in halfwords (80B; <=2-way bank alias)
// TEMP=4 -> 1/TEMP=0.25, TEMP^2=16 ; SCALE=20 ; SCALE/TEMP=5

typedef __attribute__((ext_vector_type(8))) short short8v;  // 8 bf16 (MFMA A/B frag)
typedef __attribute__((ext_vector_type(4))) float f32x4;    // MFMA C/D frag

// ---------------- reductions (blockDim.x == 256) ----------------
__device__ __forceinline__ float wave_reduce_sum(float v) {
#pragma unroll
    for (int off = 32; off; off >>= 1) v += __shfl_down(v, off, 64);
    return v;
}
__device__ __forceinline__ float wave_reduce_max(float v) {
#pragma unroll
    for (int off = 32; off; off >>= 1) v = fmaxf(v, __shfl_down(v, off, 64));
    return v;
}
__device__ __forceinline__ float block_reduce_sum(float v) {
    __shared__ float sm_s[4];
    v = wave_reduce_sum(v);
    __syncthreads();                 // protect sm_s reuse across calls
    if ((threadIdx.x & 63) == 0) sm_s[threadIdx.x >> 6] = v;
    __syncthreads();
    return sm_s[0] + sm_s[1] + sm_s[2] + sm_s[3];
}
__device__ __forceinline__ float block_reduce_max(float v) {
    __shared__ float sm_m[4];
    v = wave_reduce_max(v);
    __syncthreads();
    if ((threadIdx.x & 63) == 0) sm_m[threadIdx.x >> 6] = v;
    __syncthreads();
    return fmaxf(fmaxf(sm_m[0], sm_m[1]), fmaxf(sm_m[2], sm_m[3]));
}

// ---------------- f32 -> bf16 hi/lo split (truncation; lo = next 8 bits) ----
__device__ __forceinline__ void splitbf(float v, unsigned short& h, unsigned short& l) {
    const unsigned int b = __float_as_uint(v);
    h = (unsigned short)(b >> 16);
    const float r = v - __uint_as_float(b & 0xFFFF0000u);
    l = (unsigned short)(__float_as_uint(r) >> 16);
}
__device__ __forceinline__ void stage4(const float4 v, unsigned short* hi,
                                       unsigned short* lo, int off) {
    unsigned short h0, h1, h2, h3, l0, l1, l2, l3;
    splitbf(v.x, h0, l0); splitbf(v.y, h1, l1);
    splitbf(v.z, h2, l2); splitbf(v.w, h3, l3);
    *(ushort4*)(hi + off) = make_ushort4(h0, h1, h2, h3);
    *(ushort4*)(lo + off) = make_ushort4(l0, l1, l2, l3);
}

// ------- split-bf16 MFMA tile: 128x64 of C = A[M,K].B[N,K]^T over K-chunk.
// 3 MFMA terms (hi*hi + hi*lo + lo*hi), f32 acc -> ~2^-17 rel error. R12-proven.
__device__ __forceinline__ void gemm_tile_mfma(const float* __restrict__ A,
                                               const float* __restrict__ B,
                                               float* __restrict__ dst, int N, int K,
                                               int row0, int col0, int kbase, int kc,
                                               unsigned short* __restrict__ Ahi,
                                               unsigned short* __restrict__ Alo,
                                               unsigned short* __restrict__ Bhi,
                                               unsigned short* __restrict__ Blo) {
    constexpr int FA = BK / 4;               // 8 float4 per row K-tile
    constexpr int NA = BM * FA / 256;        // 4 per-thread A float4
    constexpr int NB = BN * FA / 256;        // 2 per-thread B float4
    const int tid = threadIdx.x;
    const int lane = tid & 63, wv = tid >> 6;
    const int fr = lane & 15, fg = lane >> 4;

    float4 pa[NA], pb[NB];
#pragma unroll
    for (int u = 0; u < NA; ++u) {
        const int t = tid + u * 256, r = t / FA, c4 = (t % FA) * 4;
        pa[u] = *(const float4*)(A + (size_t)(row0 + r) * K + kbase + c4);
    }
#pragma unroll
    for (int u = 0; u < NB; ++u) {
        const int t = tid + u * 256, r = t / FA, c4 = (t % FA) * 4;
        pb[u] = *(const float4*)(B + (size_t)(col0 + r) * K + kbase + c4);
    }
    f32x4 acc[2][4] = {};
    for (int k0 = kbase; k0 < kbase + kc; k0 += BK) {
        __syncthreads();                     // LDS reuse guard
#pragma unroll
        for (int u = 0; u < NA; ++u) {
            const int t = tid + u * 256, r = t / FA, c4 = (t % FA) * 4;
            stage4(pa[u], Ahi, Alo, r * APITCH + c4);
        }
#pragma unroll
        for (int u = 0; u < NB; ++u) {
            const int t = tid + u * 256, r = t / FA, c4 = (t % FA) * 4;
            stage4(pb[u], Bhi, Blo, r * APITCH + c4);
        }
        __syncthreads();
        if (k0 + BK < kbase + kc) {          // prefetch next K-tile into regs
            const int kn = k0 + BK;
#pragma unroll
            for (int u = 0; u < NA; ++u) {
                const int t = tid + u * 256, r = t / FA, c4 = (t % FA) * 4;
                pa[u] = *(const float4*)(A + (size_t)(row0 + r) * K + kn + c4);
            }
#pragma unroll
            for (int u = 0; u < NB; ++u) {
                const int t = tid + u * 256, r = t / FA, c4 = (t % FA) * 4;
                pb[u] = *(const float4*)(B + (size_t)(col0 + r) * K + kn + c4);
            }
        }
        short8v ah[2], al[2];
#pragma unroll
        for (int im = 0; im < 2; ++im) {
            const int mrow = (wv * 2 + im) * 16 + fr;
            ah[im] = *(short8v*)(Ahi + mrow * APITCH + fg * 8);
            al[im] = *(short8v*)(Alo + mrow * APITCH + fg * 8);
        }
#pragma unroll
        for (int in = 0; in < 4; ++in) {
            const int nrow = in * 16 + fr;
            const short8v bh = *(short8v*)(Bhi + nrow * APITCH + fg * 8);
            const short8v bl = *(short8v*)(Blo + nrow * APITCH + fg * 8);
#pragma unroll
            for (int im = 0; im < 2; ++im) {
                acc[im][in] = __builtin_amdgcn_mfma_f32_16x16x32_bf16(ah[im], bh, acc[im][in], 0, 0, 0);
                acc[im][in] = __builtin_amdgcn_mfma_f32_16x16x32_bf16(ah[im], bl, acc[im][in], 0, 0, 0);
                acc[im][in] = __builtin_amdgcn_mfma_f32_16x16x32_bf16(al[im], bh, acc[im][in], 0, 0, 0);
            }
        }
    }
    // epilogue: D col=lane&15, row=(lane>>4)*4+reg  [m89-verified]
#pragma unroll
    for (int im = 0; im < 2; ++im)
#pragma unroll
        for (int in = 0; in < 4; ++in)
#pragma unroll
            for (int r = 0; r < 4; ++r) {
                const int m = row0 + (wv * 2 + im) * 16 + fg * 4 + r;
                const int c = col0 + in * 16 + fr;
                dst[(size_t)m * N + c] = acc[im][in][r];
            }
}

// ---- K1: bid<256 -> GEMM1 split-K tile (8x2x16); bid>=256 -> sa=l2norm(seen)
__global__ __launch_bounds__(256, 2) void k1_gemm1_sanorm(const float* __restrict__ x,
                                                          const float* __restrict__ W,
                                                          const float* __restrict__ seen,
                                                          float* __restrict__ part,
                                                          float* __restrict__ sa,
                                                          int* __restrict__ doneCnt) {
    __shared__ unsigned short AhiS[BM * APITCH];
    __shared__ unsigned short AloS[BM * APITCH];
    __shared__ unsigned short BhiS[BN * APITCH];
    __shared__ unsigned short BloS[BN * APITCH];
    const int bid = blockIdx.x, tid = threadIdx.x;
    if (bid < 256) {
        const int bx = bid & 7, by = (bid >> 3) & 1, bz = bid >> 4;   // 8 x 2 x 16
        gemm_tile_mfma(x, W, part + (size_t)bz * Bn * ATT, ATT, Dd,
                       by * BM, bx * BN, bz * (Dd / SK1), Dd / SK1,
                       AhiS, AloS, BhiS, BloS);
    } else {
        if (bid == 256 && tid == 0) *doneCnt = 0;   // reset k5 completion counter
#pragma unroll
        for (int u = 0; u < 4; ++u) {
            const int r = (bid - 256) * 4 + u, c = tid * 2;
            const float2 v = *(const float2*)(seen + (size_t)r * ATT + c);
            float ss = block_reduce_sum(fmaf(v.x, v.x, v.y * v.y));
            const float sc = 1.0f / fmaxf(sqrtf(ss), 1e-12f);
            *(float2*)(sa + (size_t)r * ATT + c) = make_float2(v.x * sc, v.y * sc);
        }
    }
}

// ---- K2: ya[m] = l2norm(bias + sum_z part1[z][m][:])  (block per row)
__global__ __launch_bounds__(256) void k2_yanorm(const float* __restrict__ part,
                                                 const float* __restrict__ bias,
                                                 float* __restrict__ ya) {
    const int m = blockIdx.x, c = threadIdx.x * 2;
    float2 s = *(const float2*)(bias + c);
#pragma unroll
    for (int z = 0; z < SK1; ++z) {
        const float2 p = *(const float2*)(part + (size_t)z * Bn * ATT + (size_t)m * ATT + c);
        s.x += p.x; s.y += p.y;
    }
    float ss = block_reduce_sum(fmaf(s.x, s.x, s.y * s.y));
    const float sc = 1.0f / fmaxf(sqrtf(ss), 1e-12f);
    *(float2*)(ya + (size_t)m * ATT + c) = make_float2(s.x * sc, s.y * sc);
}

// ---- K3: GEMM2 split-K (16 x 2 x 8 = 256 blocks, KC=64)
__global__ __launch_bounds__(256, 2) void k3_gemm2(const float* __restrict__ ya,
                                                   const float* __restrict__ sa,
                                                   float* __restrict__ part) {
    __shared__ unsigned short AhiS[BM * APITCH];
    __shared__ unsigned short AloS[BM * APITCH];
    __shared__ unsigned short BhiS[BN * APITCH];
    __shared__ unsigned short BloS[BN * APITCH];
    const int bid = blockIdx.x;
    const int bx = bid & 15, by = (bid >> 4) & 1, bz = bid >> 5;   // 16 x 2 x 8
    gemm_tile_mfma(ya, sa, part + (size_t)bz * Bn * Cc, Cc, ATT,
                   by * BM, bx * BN, bz * (ATT / SK2), ATT / SK2,
                   AhiS, AloS, BhiS, BloS);
}

// ---- K4: logits = 5*sum_z part2 ; softmax -> P, negH  (block per row)
__global__ __launch_bounds__(256) void k4_softmax(const float* __restrict__ part,
                                                  float* __restrict__ P,
                                                  float* __restrict__ negH) {
    const int i = blockIdx.x, c = threadIdx.x * 4;
    float4 a = make_float4(0.f, 0.f, 0.f, 0.f);
#pragma unroll
    for (int z = 0; z < SK2; ++z) {
        const float4 p = *(const float4*)(part + (size_t)z * Bn * Cc + (size_t)i * Cc + c);
        a.x += p.x; a.y += p.y; a.z += p.z; a.w += p.w;
    }
    float lv[4] = {a.x * 5.0f, a.y * 5.0f, a.z * 5.0f, a.w * 5.0f};
    float lm = fmaxf(fmaxf(lv[0], lv[1]), fmaxf(lv[2], lv[3]));
    lm = block_reduce_max(lm);
    float se = 0.f;
#pragma unroll
    for (int k = 0; k < 4; ++k) se += __expf(lv[k] - lm);
    se = block_reduce_sum(se);
    const float logZ = __logf(se);
    float nh = 0.f;
    float4 pv;
#pragma unroll
    for (int k = 0; k < 4; ++k) {
        const float lp = lv[k] - lm - logZ;
        const float p = __expf(lp);
        (&pv.x)[k] = p;
        nh = fmaf(p, lp, nh);
    }
    *(float4*)(P + (size_t)i * Cc + c) = pv;
    nh = block_reduce_sum(nh);
    if (threadIdx.x == 0) negH[i] = nh;
}

// ---- K5: JS over masked pairs (block per row, ONE deferred reduction) +
//          last-block finalize via done-counter (signal-only; no spin wait).
__global__ __launch_bounds__(256) void k5_pairjs_fin(const float* __restrict__ P,
                                                     const float* __restrict__ negH,
                                                     const int* __restrict__ labels,
                                                     float* __restrict__ pairSum,
                                                     float* __restrict__ pairCnt,
                                                     int* __restrict__ doneCnt,
                                                     float* __restrict__ out) {
    const int i = blockIdx.x, tid = threadIdx.x;
    __shared__ int lbl[Bn];
    __shared__ float nh_s[Bn];
    __shared__ int isLast;
    lbl[tid] = labels[tid];
    nh_s[tid] = negH[tid];
    __syncthreads();
    const int li = lbl[i];
    const float4 pi = *(const float4*)(P + (size_t)i * Cc + tid * 4);
    const float nhi = nh_s[i];

    float tsum = 0.f;                 // per-thread cross-term over ALL pairs
    float nsum = 0.f, cnt = 0.f;      // tid 0 bookkeeping
    for (int j = i + 1; j < Bn; ++j) {
        if (lbl[j] != li) continue;   // uniform across block
        const float4 pj = *(const float4*)(P + (size_t)j * Cc + tid * 4);
        float t;
        t = pi.x + pj.x; tsum = fmaf(t, __logf(0.5f * t), tsum);
        t = pi.y + pj.y; tsum = fmaf(t, __logf(0.5f * t), tsum);
        t = pi.z + pj.z; tsum = fmaf(t, __logf(0.5f * t), tsum);
        t = pi.w + pj.w; tsum = fmaf(t, __logf(0.5f * t), tsum);
        if (tid == 0) { nsum += nhi + nh_s[j]; cnt += 1.0f; }
    }
    const float s = block_reduce_sum(tsum);       // ONE reduction for the row
    if (tid == 0) {
        pairSum[i] = 0.5f * (nsum - s);
        pairCnt[i] = cnt;
        __threadfence();                          // publish before signaling
        isLast = (atomicAdd(doneCnt, 1) == Bn - 1);
    }
    __syncthreads();
    if (isLast) {
        __threadfence();                          // acquire others' results
        float fs = block_reduce_sum(pairSum[tid]);
        __syncthreads();
        const float fc = block_reduce_sum(pairCnt[tid]);
        if (tid == 0) out[0] = (fc == 0.0f) ? 0.0f : (fs / fc) * 16.0f;  // * TEMP^2
    }
}

extern "C" void kernel_launch(void* const* d_in, const int* in_sizes, int n_in,
                              void* d_out, int out_size, void* d_ws, size_t ws_size,
                              hipStream_t stream) {
    const float* x      = (const float*)d_in[0];  // [256, 2048]
    const int*   labels = (const int*)d_in[1];    // [256]
    const float* W      = (const float*)d_in[2];  // [512, 2048]
    const float* bias   = (const float*)d_in[3];  // [512]
    const float* seen   = (const float*)d_in[4];  // [1024, 512]
    float* out = (float*)d_out;

    char* ws = (char*)d_ws;
    // 8 MB split-K partial region: GEMM1 (16x256x512) then GEMM2 (8x256x1024)
    float* part    = (float*)(ws);                              // 8 MB
    float* sa      = (float*)(ws + (8u << 20));                 // 2 MB
    float* ya      = (float*)(ws + (10u << 20));                // 512 KB
    float* P       = (float*)(ws + (10u << 20) + (512u << 10)); // 1 MB
    float* negH    = (float*)(ws + (11u << 20) + (512u << 10)); // 256 f32
    float* pairSum = negH + Bn;                                 // 256 f32
    float* pairCnt = pairSum + Bn;                              // 256 f32
    int*   doneCnt = (int*)(pairCnt + Bn);                      // 1 int

    k1_gemm1_sanorm<<<512, 256, 0, stream>>>(x, W, seen, part, sa, doneCnt);
    k2_yanorm<<<Bn, 256, 0, stream>>>(part, bias, ya);
    k3_gemm2<<<256, 256, 0, stream>>>(ya, sa, part);
    k4_softmax<<<Bn, 256, 0, stream>>>(part, P, negH);
    k5_pairjs_fin<<<Bn, 256, 0, stream>>>(P, negH, labels, pairSum, pairCnt, doneCnt, out);
}